// Round 4
// baseline (202.778 us; speedup 1.0000x reference)
//
#include <hip/hip_runtime.h>
#include <hip/hip_bf16.h>
#include <math.h>

#define Kn 4
#define Mm 128
#define Dd 64
#define Tt 256
#define Nn 254        // T-2
#define Cc 512        // Kn*Mm
#define ZSTRIDE 16384 // D*T
#define LSZ 65536     // per-d 256x256 bf16 L (in ushorts)

// ws float offsets. zb bf16 [d][c][s] occupies [0, 4194304); Lb bf16 follows.
#define AMU0_OFF 4194304              // 64*65536
#define AMU1_OFF 4210688
#define PLD_OFF  4227072
#define LB_OFF   4227136              // bf16 L, 64*65536 ushorts = 2,097,152 floats

typedef __attribute__((ext_vector_type(8))) short short8;
typedef __attribute__((ext_vector_type(4))) float f32x4;
typedef __attribute__((ext_vector_type(4))) unsigned short ushort4v;
typedef __attribute__((ext_vector_type(8))) unsigned short ushort8v;

#define GLD16(g, l) __builtin_amdgcn_global_load_lds( \
    (const __attribute__((address_space(1))) void*)(g), \
    (__attribute__((address_space(3))) void*)(l), 16, 0, 0)

// VALU lane broadcast: no LDS pipe, no lgkmcnt, EXEC-independent.
__device__ __forceinline__ float rdlane(float v, int l) {
  return __int_as_float(__builtin_amdgcn_readlane(__float_as_int(v), l));
}
__device__ __forceinline__ unsigned short bf16u(float v) {
  __hip_bfloat16 b = __float2bfloat16(v);
  return *(unsigned short*)&b;
}

// ---------------- K1: z -> bf16 [d][c][s] + edge passthrough (vectorized) ----
__global__ __launch_bounds__(256) void k_zcast(const float* __restrict__ z,
                                               float* __restrict__ ws,
                                               float* __restrict__ out) {
  int rid = blockIdx.x * 4 + (threadIdx.x >> 6);   // 0..32767 = d*512 + c
  int lane = threadIdx.x & 63;
  int dd = rid >> 9, cc = rid & 511;
  const float* zr = z + cc * ZSTRIDE + dd * Tt;
  unsigned short* zbr = (unsigned short*)ws + (dd * 512 + cc) * 256;
  // zb[s] = z[s+1] for s<254, else 0. lane covers s = 4*lane..4*lane+3.
  float4 v = *(const float4*)(zr + lane * 4);
  float nx = __shfl_down(v.x, 1);                  // next lane's z[4l+4]
  float e0 = v.y, e1 = v.z, e2 = v.w, e3 = nx;
  if (lane == 63) { e2 = 0.f; e3 = 0.f; }          // s = 254, 255
  union { ushort4v u; unsigned short s[4]; } o;
  o.s[0] = bf16u(e0); o.s[1] = bf16u(e1); o.s[2] = bf16u(e2); o.s[3] = bf16u(e3);
  *(ushort4v*)(zbr + lane * 4) = o.u;
  if (lane == 0)  out[cc * ZSTRIDE + dd * Tt] = v.x;         // z[0]
  if (lane == 63) out[cc * ZSTRIDE + dd * Tt + 255] = v.w;   // z[255]
}

// ---------------- K2: fused left-looking Cholesky, one block per d ----------------
// v3: PB=16 panels. Unrolled readlane triangles shrink 4x (I$ + SGPR-hazard
// relief); total broadcast-pair count halves (work moves into MFMA history,
// which runs as 32-col 16x16x32 chunks with a guarded half-chunk tail).
#define PB 16
#define PSTRIDE 257   // col-major P: conflict-lite

// Packed L row base (ushort units). Row r, band q=r>>4 holds (q+1)*16 cols,
// padded to 2q+3 16B-chunks (odd) so strided fragment reads stay conflict-lite.
// Total: 16 * sum_{q=0..15}(2q+3) = 4608 chunks = 73728 B.
__device__ __forceinline__ int lrow_base(int r) {
  int q = r >> 4;
  return (16 * (q * q + 2 * q) + (r & 15) * (2 * q + 3)) * 8;
}

__global__ __launch_bounds__(256) void k_chol(const float* __restrict__ log_tau,
                                              float* __restrict__ ws) {
  const int d = blockIdx.x;
  const int tid = threadIdx.x;
  const int lane = tid & 63, w = tid >> 6;
  const int m16 = lane & 15, quad = lane >> 4;
  __shared__ unsigned short Lp[36864];   // 72 KB packed triangular bf16 L
  __shared__ float g[256];
  __shared__ float a0s[256], a1s[256];
  __shared__ float P[PB * PSTRIDE];      // col-major: P[c*PSTRIDE + r]
  __shared__ float logtot;

  // zero packed L (rows 254/255 + anything unwritten must read as 0)
  {
    f32x4 zz = (f32x4){0.f, 0.f, 0.f, 0.f};
#pragma unroll
    for (int i = 0; i < 18; ++i)
      *(f32x4*)&Lp[(tid * 18 + i) * 8] = zz;   // 256*18*16B = 73728 B exact
  }

  // build g, Amu (also export Amu for k_gemm)
  float tau = expf(log_tau[d]);
  float inv2 = 1.0f / (2.0f * tau * tau);
  float lf = (float)tid;
  g[tid] = expf(-(lf * lf) * inv2);
  if (tid == 0) logtot = 0.f;
  __syncthreads();
  {
    float b = g[255];
    float det = 1.0f - b * b;
    float a0 = 0.f, a1 = 0.f;
    if (tid < Nn) {
      float kp0 = g[tid + 1], kp1 = g[254 - tid];
      a0 = (kp0 - b * kp1) / det;
      a1 = (kp1 - b * kp0) / det;
    }
    a0s[tid] = a0; a1s[tid] = a1;
    ws[AMU0_OFF + d * 256 + tid] = a0;
    ws[AMU1_OFF + d * 256 + tid] = a1;
  }
  __syncthreads();

  for (int p = 0; p < 16; ++p) {
    const int j0 = p * PB;
    const int m = Nn - j0;                // 254 - 16p > 0 for all p<16
    const int bw = (m < PB) ? m : PB;

    // ---- per-wave: build Schur panel slab (64 rows x 16 cols) ----
    if (w * 64 < m) {
      f32x4 acc[4];
      const int s = j0 + m16;             // <= 255 (junk cols ok)
      const int e1 = s + 1 > 255 ? 255 : s + 1;
      const int e2 = 254 - s < 0 ? 0 : 254 - s;
      const float ge1 = g[e1], ge2 = g[e2];
#pragma unroll
      for (int ti = 0; ti < 4; ++ti)
#pragma unroll
        for (int rg = 0; rg < 4; ++rg) {
          int rl = w * 64 + ti * 16 + quad * 4 + rg;
          int t = j0 + rl;
          float v = 0.f;
          if (rl < m) {                   // t < Nn
            int lag = t - s; lag = lag < 0 ? -lag : lag;
            v = g[lag] - a0s[t] * ge1 - a1s[t] * ge2;
            if (t == s) v += 1e-5f;
          }
          acc[ti][rg] = v;
        }
      // history: acc += Lrows * (-Lcols)^T over cols [0, j0), 32-col chunks
      int bbase = lrow_base(j0 + m16) + quad * 8;
      int abase[4];
#pragma unroll
      for (int ti = 0; ti < 4; ++ti) {
        int row = j0 + w * 64 + ti * 16 + m16;
        if (row > 255) row = 255;         // rows 254/255 are all-zero
        abase[ti] = lrow_base(row) + quad * 8;
      }
      const int nch = (p + 1) >> 1;       // 32-col chunks covering 16p cols
      for (int c32 = 0; c32 < nch; ++c32) {
        const int k0 = c32 * 32;
        const bool full = (k0 + 32 <= j0);
        const bool ld = full | (quad < 2);  // half-chunk: quads 2,3 -> zero
        short8 bfr;
        {
          union { short8 s; unsigned int u[4]; } nb;
          nb.s = (short8){0,0,0,0,0,0,0,0};
          if (ld) nb.s = *(const short8*)&Lp[bbase + k0];
          nb.u[0] ^= 0x80008000u; nb.u[1] ^= 0x80008000u;
          nb.u[2] ^= 0x80008000u; nb.u[3] ^= 0x80008000u;
          bfr = nb.s;
        }
        short8 afr[4];
#pragma unroll
        for (int ti = 0; ti < 4; ++ti) {
          afr[ti] = (short8){0,0,0,0,0,0,0,0};
          if (ld) afr[ti] = *(const short8*)&Lp[abase[ti] + k0];
        }
#pragma unroll
        for (int ti = 0; ti < 4; ++ti)
          acc[ti] = __builtin_amdgcn_mfma_f32_16x16x32_bf16(afr[ti], bfr, acc[ti], 0, 0, 0);
      }
      // dump slab to LDS panel (D layout: row = quad*4+rg, col = m16)
#pragma unroll
      for (int ti = 0; ti < 4; ++ti)
#pragma unroll
        for (int rg = 0; rg < 4; ++rg) {
          int rl = w * 64 + ti * 16 + quad * 4 + rg;
          if (rl < m) P[m16 * PSTRIDE + rl] = acc[ti][rg];
        }
    }
    __syncthreads();

    // ---- phase A: 16x16 register LDL, redundant per wave, readlane bcasts ----
    float aA[PB];
    float rinv = 0.f, dr = 1.0f, diagv = 0.f;
    if (lane < PB) {
#pragma unroll
      for (int c = 0; c < PB; ++c) aA[c] = P[c * PSTRIDE + lane];
#pragma unroll
      for (int j = 0; j < PB; ++j) {
        float pj = rdlane(aA[j], j);
        if (lane == j) dr = pj;
        float s = aA[j] * __builtin_amdgcn_rcpf(pj);
#pragma unroll
        for (int k = j + 1; k < PB; ++k)
          aA[k] -= s * rdlane(aA[j], k);
      }
      rinv = __builtin_amdgcn_rsqf(dr);
      diagv = dr * rinv;                  // ~sqrt(dr)
    }
    // wave 0 only: logdet + normalized diag-block rows -> Lp
    if (w == 0 && lane < PB) {
      float lv = (lane < bw) ? 0.5f * logf(fabsf(dr)) : 0.f;
      lv += __shfl_xor(lv, 8, 16);
      lv += __shfl_xor(lv, 4, 16);
      lv += __shfl_xor(lv, 2, 16);
      lv += __shfl_xor(lv, 1, 16);
      if (lane == 0) logtot += lv;
      if (lane < m) {
        unsigned short* lrow = Lp + lrow_base(j0 + lane) + j0;
        union { ushort8v u8[2]; unsigned short s[16]; } o;
#pragma unroll
        for (int c = 0; c < PB; ++c) {
          float v = 0.f;
          if (c < bw) {
            if (c < lane)       v = aA[c] * rdlane(rinv, c);
            else if (c == lane) v = diagv;
          }
          o.s[c] = bf16u(v);
        }
        *(ushort8v*)(lrow) = o.u8[0];
        *(ushort8v*)(lrow + 8) = o.u8[1];
      }
    }

    // ---- TRSM: rows PB..m-1, thread-per-row, readlane from own wave's factor ----
    const int nrows = m - bw;             // >0 only when bw==PB
    if (tid < nrows) {
      const int ri = PB + tid;
      float b[PB];
#pragma unroll
      for (int c = 0; c < PB; ++c) b[c] = P[c * PSTRIDE + ri];
#pragma unroll
      for (int j = 0; j < PB; ++j) {
        float rj = rdlane(rinv, j);
        float xj = b[j] * rj;             // final L entry (normalized)
        float t2 = xj * rj;               // b[j] / dr_j
#pragma unroll
        for (int k = j + 1; k < PB; ++k)
          b[k] -= t2 * rdlane(aA[j], k);  // a_k[j] = dr_j * L_u[k][j]
        b[j] = xj;
      }
      unsigned short* lrow = Lp + lrow_base(j0 + ri) + j0;
      union { ushort8v u8[2]; unsigned short s[16]; } o;
#pragma unroll
      for (int c = 0; c < PB; ++c) o.s[c] = bf16u(b[c]);
      *(ushort8v*)(lrow) = o.u8[0];
      *(ushort8v*)(lrow + 8) = o.u8[1];
    }
    __syncthreads();   // Lp writes visible for next panel's history reads
  }

  // ---- final dump: dense bf16 L (incl. zero upper triangle) to global ----
  // 8 rows x 32 chunks x 16B per iter, coalesced 16B stores.
  unsigned short* LbG = (unsigned short*)(ws + LB_OFF) + (size_t)d * LSZ;
  int rgrp = tid >> 5, ch = tid & 31;
#pragma unroll
  for (int it = 0; it < 32; ++it) {
    int r = it * 8 + rgrp;
    int q = r >> 4;
    f32x4 v = (f32x4){0.f, 0.f, 0.f, 0.f};
    if (ch < 2 * (q + 1)) v = *(const f32x4*)&Lp[lrow_base(r) + ch * 8];
    *(f32x4*)&LbG[r * 256 + ch * 8] = v;
  }
  if (tid == 0) ws[PLD_OFF + d] = logtot;
}

// ---------------- K3: logdet reduce + scalar output ----------------
__global__ void k_logdet(const float* __restrict__ ws, const float* __restrict__ sldj,
                         float* __restrict__ out) {
  int tid = threadIdx.x;  // 64 threads
  float v = ws[PLD_OFF + tid];
  for (int off = 32; off > 0; off >>= 1) v += __shfl_down(v, off);
  if (tid == 0) out[8388608] = sldj[0] + v;   // Cc*ZSTRIDE
}

// ---------------- K4: MFMA bf16 GEMM: out[c,1+t] = sum_s z[c,s]*L[t,s] + mu ----
__global__ __launch_bounds__(256) void k_gemm(const float* __restrict__ z,
                                              const float* __restrict__ ws,
                                              float* __restrict__ out) {
  const int d = blockIdx.z;
  const int t0 = blockIdx.y * 128;
  const int c0 = blockIdx.x * 128;
  const int tid = threadIdx.x;
  const unsigned short* zb = (const unsigned short*)ws + d * (512 * 256);
  const unsigned short* lb = (const unsigned short*)(ws + LB_OFF) + d * LSZ;
  __shared__ unsigned short As[128 * 32];   // [c][s] bf16
  __shared__ unsigned short Bs[128 * 32];   // [t][s] bf16
  f32x4 acc[4][4];
#pragma unroll
  for (int mi = 0; mi < 4; ++mi)
#pragma unroll
    for (int ni = 0; ni < 4; ++ni)
      acc[mi][ni] = (f32x4){0.f, 0.f, 0.f, 0.f};

  const int l = tid & 63, w = tid >> 6;
  const int wm = w & 1, wn = w >> 1;       // wave tile: c += wm*64, t += wn*64
  const int m16 = l & 15, quad = l >> 4;

  const int nks = (blockIdx.y == 0) ? 4 : 8;   // L[t<128][s>=128]==0 -> skip
  for (int ks = 0; ks < nks; ++ks) {
    const int s0 = ks * 32;
#pragma unroll
    for (int i = 0; i < 2; ++i) {
      int e = i * 256 + tid;
      int row = e >> 2, half = e & 3;      // 4x16B chunks per 32-bf16 row
      GLD16(zb + (c0 + row) * 256 + s0 + half * 8, &As[e * 8]);
      GLD16(lb + (t0 + row) * 256 + s0 + half * 8, &Bs[e * 8]);
    }
    __syncthreads();
    short8 af[4], bf[4];
#pragma unroll
    for (int mi = 0; mi < 4; ++mi)
      af[mi] = *(const short8*)&As[(wm * 64 + mi * 16 + m16) * 32 + quad * 8];
#pragma unroll
    for (int ni = 0; ni < 4; ++ni)
      bf[ni] = *(const short8*)&Bs[(wn * 64 + ni * 16 + m16) * 32 + quad * 8];
#pragma unroll
    for (int mi = 0; mi < 4; ++mi)
#pragma unroll
      for (int ni = 0; ni < 4; ++ni)
        acc[mi][ni] = __builtin_amdgcn_mfma_f32_16x16x32_bf16(af[mi], bf[ni], acc[mi][ni], 0, 0, 0);
    __syncthreads();
  }

  // epilogue: + Amu0[t]*z[c,0] + Amu1[t]*z[c,255]; store
  const float* Amu0 = ws + AMU0_OFF + d * 256;
  const float* Amu1 = ws + AMU1_OFF + d * 256;
  float a0v[4], a1v[4];
#pragma unroll
  for (int ni = 0; ni < 4; ++ni) {
    int t_ = t0 + wn * 64 + ni * 16 + m16;
    a0v[ni] = Amu0[t_]; a1v[ni] = Amu1[t_];
  }
#pragma unroll
  for (int mi = 0; mi < 4; ++mi) {
#pragma unroll
    for (int rg = 0; rg < 4; ++rg) {
      int c_ = c0 + wm * 64 + mi * 16 + quad * 4 + rg;
      const float* zc = z + c_ * ZSTRIDE + d * Tt;
      float z0 = zc[0], z1 = zc[255];
      float* op = out + c_ * ZSTRIDE + d * Tt + 1;
#pragma unroll
      for (int ni = 0; ni < 4; ++ni) {
        int t_ = t0 + wn * 64 + ni * 16 + m16;
        float v = acc[mi][ni][rg] + a0v[ni] * z0 + a1v[ni] * z1;
        if (t_ < Nn) op[t_] = v;
      }
    }
  }
}

extern "C" void kernel_launch(void* const* d_in, const int* in_sizes, int n_in,
                              void* d_out, int out_size, void* d_ws, size_t ws_size,
                              hipStream_t stream) {
  const float* z = (const float*)d_in[0];
  const float* sldj = (const float*)d_in[1];
  const float* log_tau = (const float*)d_in[2];
  float* out = (float*)d_out;
  float* ws = (float*)d_ws;

  hipLaunchKernelGGL(k_chol, dim3(Dd), dim3(256), 0, stream, log_tau, ws);
  hipLaunchKernelGGL(k_zcast, dim3(8192), dim3(256), 0, stream, z, ws, out);
  hipLaunchKernelGGL(k_logdet, dim3(1), dim3(64), 0, stream, ws, sldj, out);
  hipLaunchKernelGGL(k_gemm, dim3(4, 2, Dd), dim3(256), 0, stream, z, ws, out);
}

// Round 5
// 195.536 us; speedup vs baseline: 1.0370x; 1.0370x over previous
//
#include <hip/hip_runtime.h>
#include <hip/hip_bf16.h>
#include <math.h>

#define Kn 4
#define Mm 128
#define Dd 64
#define Tt 256
#define Nn 254        // T-2
#define Cc 512        // Kn*Mm
#define ZSTRIDE 16384 // D*T
#define LSZ 65536     // per-d 256x256 bf16 L (in ushorts)

// ws float offsets. zb bf16 [d][c][s] occupies [0, 4194304); Lb bf16 follows.
#define AMU0_OFF 4194304              // 64*65536
#define AMU1_OFF 4210688
#define PLD_OFF  4227072
#define LB_OFF   4227136              // bf16 L, 64*65536 ushorts = 2,097,152 floats

typedef __attribute__((ext_vector_type(8))) short short8;
typedef __attribute__((ext_vector_type(4))) float f32x4;
typedef __attribute__((ext_vector_type(4))) unsigned short ushort4v;
typedef __attribute__((ext_vector_type(8))) unsigned short ushort8v;

#define GLD16(g, l) __builtin_amdgcn_global_load_lds( \
    (const __attribute__((address_space(1))) void*)(g), \
    (__attribute__((address_space(3))) void*)(l), 16, 0, 0)

// VALU lane broadcast: no LDS pipe, no lgkmcnt, EXEC-independent.
__device__ __forceinline__ float rdlane(float v, int l) {
  return __int_as_float(__builtin_amdgcn_readlane(__float_as_int(v), l));
}
__device__ __forceinline__ unsigned short bf16u(float v) {
  __hip_bfloat16 b = __float2bfloat16(v);
  return *(unsigned short*)&b;
}

#define PB 16
#define PSTRIDE 257   // col-major P: conflict-lite

// Packed L row base (ushort units). Row r, band q=r>>4 holds (q+1)*16 cols,
// padded to 2q+3 16B-chunks (odd) so strided fragment reads stay conflict-lite.
// Total: 16 * sum_{q=0..15}(2q+3) = 4608 chunks = 73728 B.
__device__ __forceinline__ int lrow_base(int r) {
  int q = r >> 4;
  return (16 * (q * q + 2 * q) + (r & 15) * (2 * q + 3)) * 8;
}

// ---------------- K1: fused chol (blocks 0..63) + zcast (blocks 64..1087) ----
// chol and zcast are mutually independent; zcast's pure-BW work runs on the
// ~192 CUs that chol leaves idle, fully hidden behind chol's latency chains.
__global__ __launch_bounds__(256) void k_main(const float* __restrict__ z,
                                              const float* __restrict__ log_tau,
                                              float* __restrict__ ws,
                                              float* __restrict__ out) {
  const int tid = threadIdx.x;
  const int lane = tid & 63, w = tid >> 6;

  if (blockIdx.x >= 64) {
    // ---------------- zcast role: 1024 blocks x 32 rids ----------------
    const int bz = blockIdx.x - 64;            // 0..1023
#pragma unroll
    for (int i = 0; i < 8; ++i) {
      int rid = (bz * 4 + w) * 8 + i;          // 0..32767 = d*512 + c
      int dd = rid >> 9, cc = rid & 511;
      const float* zr = z + cc * ZSTRIDE + dd * Tt;
      unsigned short* zbr = (unsigned short*)ws + (dd * 512 + cc) * 256;
      // zb[s] = z[s+1] for s<254, else 0. lane covers s = 4*lane..4*lane+3.
      float4 v = *(const float4*)(zr + lane * 4);
      float nx = __shfl_down(v.x, 1);          // next lane's z[4l+4]
      float e0 = v.y, e1 = v.z, e2 = v.w, e3 = nx;
      if (lane == 63) { e2 = 0.f; e3 = 0.f; }  // s = 254, 255
      union { ushort4v u; unsigned short s[4]; } o;
      o.s[0] = bf16u(e0); o.s[1] = bf16u(e1); o.s[2] = bf16u(e2); o.s[3] = bf16u(e3);
      *(ushort4v*)(zbr + lane * 4) = o.u;
      if (lane == 0)  out[cc * ZSTRIDE + dd * Tt] = v.x;         // z[0]
      if (lane == 63) out[cc * ZSTRIDE + dd * Tt + 255] = v.w;   // z[255]
    }
    return;
  }

  // ---------------- chol role: one block per d ----------------
  const int d = blockIdx.x;
  const int m16 = lane & 15, quad = lane >> 4;
  __shared__ unsigned short Lp[36864];   // 72 KB packed triangular bf16 L
  __shared__ float g[256];
  __shared__ float a0s[256], a1s[256];
  __shared__ float P[PB * PSTRIDE];      // col-major: P[c*PSTRIDE + r]
  __shared__ float logtot;

  // zero packed L (rows 254/255 + anything unwritten must read as 0)
  {
    f32x4 zz = (f32x4){0.f, 0.f, 0.f, 0.f};
#pragma unroll
    for (int i = 0; i < 18; ++i)
      *(f32x4*)&Lp[(tid * 18 + i) * 8] = zz;   // 256*18*16B = 73728 B exact
  }

  // build g, Amu (also export Amu for k_gemm)
  float tau = expf(log_tau[d]);
  float inv2 = 1.0f / (2.0f * tau * tau);
  float lf = (float)tid;
  g[tid] = expf(-(lf * lf) * inv2);
  if (tid == 0) logtot = 0.f;
  __syncthreads();
  {
    float b = g[255];
    float det = 1.0f - b * b;
    float a0 = 0.f, a1 = 0.f;
    if (tid < Nn) {
      float kp0 = g[tid + 1], kp1 = g[254 - tid];
      a0 = (kp0 - b * kp1) / det;
      a1 = (kp1 - b * kp0) / det;
    }
    a0s[tid] = a0; a1s[tid] = a1;
    ws[AMU0_OFF + d * 256 + tid] = a0;
    ws[AMU1_OFF + d * 256 + tid] = a1;
  }
  __syncthreads();

  for (int p = 0; p < 16; ++p) {
    const int j0 = p * PB;
    const int m = Nn - j0;                // 254 - 16p > 0 for all p<16
    const int bw = (m < PB) ? m : PB;

    // ---- per-wave: build Schur panel slab (64 rows x 16 cols) ----
    if (w * 64 < m) {
      f32x4 acc[4];
      const int s = j0 + m16;             // <= 255 (junk cols ok)
      const int e1 = s + 1 > 255 ? 255 : s + 1;
      const int e2 = 254 - s < 0 ? 0 : 254 - s;
      const float ge1 = g[e1], ge2 = g[e2];
#pragma unroll
      for (int ti = 0; ti < 4; ++ti)
#pragma unroll
        for (int rg = 0; rg < 4; ++rg) {
          int rl = w * 64 + ti * 16 + quad * 4 + rg;
          int t = j0 + rl;
          float v = 0.f;
          if (rl < m) {                   // t < Nn
            int lag = t - s; lag = lag < 0 ? -lag : lag;
            v = g[lag] - a0s[t] * ge1 - a1s[t] * ge2;
            if (t == s) v += 1e-5f;
          }
          acc[ti][rg] = v;
        }
      // history: acc += Lrows * (-Lcols)^T over cols [0, j0), 32-col chunks,
      // software-pipelined: prefetch chunk c+1's 5 ds_read_b128 before the
      // MFMAs of chunk c (hides the ~2x LDS latency pocket per chunk).
      int bbase = lrow_base(j0 + m16) + quad * 8;
      int abase[4];
#pragma unroll
      for (int ti = 0; ti < 4; ++ti) {
        int row = j0 + w * 64 + ti * 16 + m16;
        if (row > 255) row = 255;         // rows 254/255 are all-zero
        abase[ti] = lrow_base(row) + quad * 8;
      }
      const int nch = (p + 1) >> 1;       // 32-col chunks covering 16p cols
#define LOADCH(c32_, bo_, ao_) do {                                   \
        const int k0_ = (c32_) * 32;                                  \
        const bool full_ = (k0_ + 32 <= j0);                          \
        const bool ld_ = full_ | (quad < 2);                          \
        bo_ = (short8){0,0,0,0,0,0,0,0};                              \
        if (ld_) bo_ = *(const short8*)&Lp[bbase + k0_];              \
        _Pragma("unroll")                                             \
        for (int ti_ = 0; ti_ < 4; ++ti_) {                           \
          ao_[ti_] = (short8){0,0,0,0,0,0,0,0};                       \
          if (ld_) ao_[ti_] = *(const short8*)&Lp[abase[ti_] + k0_];  \
        }                                                             \
      } while (0)
      if (nch > 0) {
        short8 bcur, acur[4];
        LOADCH(0, bcur, acur);
        for (int c32 = 0; c32 < nch; ++c32) {
          short8 bnxt, anxt[4];
          const bool have_nxt = (c32 + 1 < nch);
          if (have_nxt) LOADCH(c32 + 1, bnxt, anxt);
          union { short8 s; unsigned int u[4]; } nb;
          nb.s = bcur;
          nb.u[0] ^= 0x80008000u; nb.u[1] ^= 0x80008000u;
          nb.u[2] ^= 0x80008000u; nb.u[3] ^= 0x80008000u;
#pragma unroll
          for (int ti = 0; ti < 4; ++ti)
            acc[ti] = __builtin_amdgcn_mfma_f32_16x16x32_bf16(acur[ti], nb.s, acc[ti], 0, 0, 0);
          if (have_nxt) {
            bcur = bnxt;
#pragma unroll
            for (int ti = 0; ti < 4; ++ti) acur[ti] = anxt[ti];
          }
        }
      }
#undef LOADCH
      // dump slab to LDS panel (D layout: row = quad*4+rg, col = m16)
#pragma unroll
      for (int ti = 0; ti < 4; ++ti)
#pragma unroll
        for (int rg = 0; rg < 4; ++rg) {
          int rl = w * 64 + ti * 16 + quad * 4 + rg;
          if (rl < m) P[m16 * PSTRIDE + rl] = acc[ti][rg];
        }
    }
    __syncthreads();

    // ---- phase A: 16x16 register LDL, redundant per wave, readlane bcasts ----
    float aA[PB];
    float rinv = 0.f, dr = 1.0f, diagv = 0.f;
    if (lane < PB) {
#pragma unroll
      for (int c = 0; c < PB; ++c) aA[c] = P[c * PSTRIDE + lane];
#pragma unroll
      for (int j = 0; j < PB; ++j) {
        float pj = rdlane(aA[j], j);
        if (lane == j) dr = pj;
        float s = aA[j] * __builtin_amdgcn_rcpf(pj);
#pragma unroll
        for (int k = j + 1; k < PB; ++k)
          aA[k] -= s * rdlane(aA[j], k);
      }
      rinv = __builtin_amdgcn_rsqf(dr);
      diagv = dr * rinv;                  // ~sqrt(dr)
    }
    // wave 0 only: logdet + normalized diag-block rows -> Lp
    if (w == 0 && lane < PB) {
      float lv = (lane < bw) ? 0.5f * logf(fabsf(dr)) : 0.f;
      lv += __shfl_xor(lv, 8, 16);
      lv += __shfl_xor(lv, 4, 16);
      lv += __shfl_xor(lv, 2, 16);
      lv += __shfl_xor(lv, 1, 16);
      if (lane == 0) logtot += lv;
      if (lane < m) {
        unsigned short* lrow = Lp + lrow_base(j0 + lane) + j0;
        union { ushort8v u8[2]; unsigned short s[16]; } o;
#pragma unroll
        for (int c = 0; c < PB; ++c) {
          float v = 0.f;
          if (c < bw) {
            if (c < lane)       v = aA[c] * rdlane(rinv, c);
            else if (c == lane) v = diagv;
          }
          o.s[c] = bf16u(v);
        }
        *(ushort8v*)(lrow) = o.u8[0];
        *(ushort8v*)(lrow + 8) = o.u8[1];
      }
    }

    // ---- TRSM: rows PB..m-1, thread-per-row, readlane from own wave's factor ----
    const int nrows = m - bw;             // >0 only when bw==PB
    if (tid < nrows) {
      const int ri = PB + tid;
      float b[PB];
#pragma unroll
      for (int c = 0; c < PB; ++c) b[c] = P[c * PSTRIDE + ri];
#pragma unroll
      for (int j = 0; j < PB; ++j) {
        float rj = rdlane(rinv, j);
        float xj = b[j] * rj;             // final L entry (normalized)
        float t2 = xj * rj;               // b[j] / dr_j
#pragma unroll
        for (int k = j + 1; k < PB; ++k)
          b[k] -= t2 * rdlane(aA[j], k);  // a_k[j] = dr_j * L_u[k][j]
        b[j] = xj;
      }
      unsigned short* lrow = Lp + lrow_base(j0 + ri) + j0;
      union { ushort8v u8[2]; unsigned short s[16]; } o;
#pragma unroll
      for (int c = 0; c < PB; ++c) o.s[c] = bf16u(b[c]);
      *(ushort8v*)(lrow) = o.u8[0];
      *(ushort8v*)(lrow + 8) = o.u8[1];
    }
    __syncthreads();   // Lp writes visible for next panel's history reads
  }

  // ---- final dump: dense bf16 L (incl. zero upper triangle) to global ----
  // 8 rows x 32 chunks x 16B per iter, coalesced 16B stores.
  unsigned short* LbG = (unsigned short*)(ws + LB_OFF) + (size_t)d * LSZ;
  int rgrp = tid >> 5, ch = tid & 31;
#pragma unroll
  for (int it = 0; it < 32; ++it) {
    int r = it * 8 + rgrp;
    int q = r >> 4;
    f32x4 v = (f32x4){0.f, 0.f, 0.f, 0.f};
    if (ch < 2 * (q + 1)) v = *(const f32x4*)&Lp[lrow_base(r) + ch * 8];
    *(f32x4*)&LbG[r * 256 + ch * 8] = v;
  }
  if (tid == 0) ws[PLD_OFF + d] = logtot;
}

// ---------------- K2: MFMA bf16 GEMM + fused logdet ----------------
// out[c,1+t] = sum_s z[c,s]*L[t,s] + mu; block (0,0,0) also reduces logdet.
__global__ __launch_bounds__(256) void k_gemm(const float* __restrict__ z,
                                              const float* __restrict__ ws,
                                              const float* __restrict__ sldj,
                                              float* __restrict__ out) {
  const int d = blockIdx.z;
  const int t0 = blockIdx.y * 128;
  const int c0 = blockIdx.x * 128;
  const int tid = threadIdx.x;
  const unsigned short* zb = (const unsigned short*)ws + d * (512 * 256);
  const unsigned short* lb = (const unsigned short*)(ws + LB_OFF) + d * LSZ;
  __shared__ unsigned short As[128 * 32];   // [c][s] bf16
  __shared__ unsigned short Bs[128 * 32];   // [t][s] bf16
  f32x4 acc[4][4];
#pragma unroll
  for (int mi = 0; mi < 4; ++mi)
#pragma unroll
    for (int ni = 0; ni < 4; ++ni)
      acc[mi][ni] = (f32x4){0.f, 0.f, 0.f, 0.f};

  const int l = tid & 63, w = tid >> 6;
  const int wm = w & 1, wn = w >> 1;       // wave tile: c += wm*64, t += wn*64
  const int m16 = l & 15, quad = l >> 4;

  // fused logdet reduce (block (0,0,0), wave 3 lanes 0..63)
  if (blockIdx.x == 0 && blockIdx.y == 0 && d == 0 && w == 3) {
    float v = ws[PLD_OFF + l];
    for (int off = 32; off > 0; off >>= 1) v += __shfl_down(v, off);
    if (l == 0) out[8388608] = sldj[0] + v;   // Cc*ZSTRIDE
  }

  const int nks = (blockIdx.y == 0) ? 4 : 8;   // L[t<128][s>=128]==0 -> skip
  for (int ks = 0; ks < nks; ++ks) {
    const int s0 = ks * 32;
#pragma unroll
    for (int i = 0; i < 2; ++i) {
      int e = i * 256 + tid;
      int row = e >> 2, half = e & 3;      // 4x16B chunks per 32-bf16 row
      GLD16(zb + (c0 + row) * 256 + s0 + half * 8, &As[e * 8]);
      GLD16(lb + (t0 + row) * 256 + s0 + half * 8, &Bs[e * 8]);
    }
    __syncthreads();
    short8 af[4], bf[4];
#pragma unroll
    for (int mi = 0; mi < 4; ++mi)
      af[mi] = *(const short8*)&As[(wm * 64 + mi * 16 + m16) * 32 + quad * 8];
#pragma unroll
    for (int ni = 0; ni < 4; ++ni)
      bf[ni] = *(const short8*)&Bs[(wn * 64 + ni * 16 + m16) * 32 + quad * 8];
#pragma unroll
    for (int mi = 0; mi < 4; ++mi)
#pragma unroll
      for (int ni = 0; ni < 4; ++ni)
        acc[mi][ni] = __builtin_amdgcn_mfma_f32_16x16x32_bf16(af[mi], bf[ni], acc[mi][ni], 0, 0, 0);
    __syncthreads();
  }

  // epilogue: + Amu0[t]*z[c,0] + Amu1[t]*z[c,255]; store
  const float* Amu0 = ws + AMU0_OFF + d * 256;
  const float* Amu1 = ws + AMU1_OFF + d * 256;
  float a0v[4], a1v[4];
#pragma unroll
  for (int ni = 0; ni < 4; ++ni) {
    int t_ = t0 + wn * 64 + ni * 16 + m16;
    a0v[ni] = Amu0[t_]; a1v[ni] = Amu1[t_];
  }
#pragma unroll
  for (int mi = 0; mi < 4; ++mi) {
#pragma unroll
    for (int rg = 0; rg < 4; ++rg) {
      int c_ = c0 + wm * 64 + mi * 16 + quad * 4 + rg;
      const float* zc = z + c_ * ZSTRIDE + d * Tt;
      float z0 = zc[0], z1 = zc[255];
      float* op = out + c_ * ZSTRIDE + d * Tt + 1;
#pragma unroll
      for (int ni = 0; ni < 4; ++ni) {
        int t_ = t0 + wn * 64 + ni * 16 + m16;
        float v = acc[mi][ni][rg] + a0v[ni] * z0 + a1v[ni] * z1;
        if (t_ < Nn) op[t_] = v;
      }
    }
  }
}

extern "C" void kernel_launch(void* const* d_in, const int* in_sizes, int n_in,
                              void* d_out, int out_size, void* d_ws, size_t ws_size,
                              hipStream_t stream) {
  const float* z = (const float*)d_in[0];
  const float* sldj = (const float*)d_in[1];
  const float* log_tau = (const float*)d_in[2];
  float* out = (float*)d_out;
  float* ws = (float*)d_ws;

  hipLaunchKernelGGL(k_main, dim3(1088), dim3(256), 0, stream, z, log_tau, ws, out);
  hipLaunchKernelGGL(k_gemm, dim3(4, 2, Dd), dim3(256), 0, stream, z, ws, sldj, out);
}